// Round 6
// baseline (218.056 us; speedup 1.0000x reference)
//
#include <hip/hip_runtime.h>

#define NB 32
#define ND 64
#define NT 4096
#define NK 512

typedef __attribute__((ext_vector_type(8))) short short8;
typedef __attribute__((ext_vector_type(16))) float f32x16;
typedef unsigned int uint32;
typedef unsigned short ushort16_t;

#define PERM(r) ((((r) & 7) * 16) + ((r) >> 3))
#define STR 68
#define MARGIN 4e-4f

__device__ __forceinline__ ushort16_t bf16rne(float f) {
    uint32 u = __float_as_uint(f);
    return (ushort16_t)((u + 0x7FFFu + ((u >> 16) & 1u)) >> 16);
}
__device__ __forceinline__ float bf16tof(ushort16_t h) {
    return __uint_as_float(((uint32)h) << 16);
}

// ---------------------------------------------------------------------------
// prep: blocks 0..15 pack cb into MFMA A-operand bf16 hi/lo fragments
// (slot j of lane L in (chunk c, kstep s) holds cb[c*32+(L&31)][s*16+(L>>5)*8+j]);
// block 16 computes exact numpy-pairwise enorm[512] (verified code, R1-R5).
// ---------------------------------------------------------------------------
__global__ void prep_kernel(const float* __restrict__ cb,
                            uint4* __restrict__ cbfrag,
                            float* __restrict__ enorm) {
    const int bi = blockIdx.x, tid = threadIdx.x;
    if (bi < 16) {
        const int t = bi * 256 + tid;            // (c,s,L) in 16*4*64
        const int c = t >> 8, rem = t & 255, s = rem >> 6, L = rem & 63;
        const int kcode = c * 32 + (L & 31);
        const int dbase = s * 16 + ((L >> 5) << 3);
        const float* src = cb + (size_t)kcode * 64 + dbase;
        const float4 pa = *(const float4*)src;
        const float4 pb = *(const float4*)(src + 4);
        const float f[8] = {pa.x, pa.y, pa.z, pa.w, pb.x, pb.y, pb.z, pb.w};
        uint32 hw[4], lw[4];
#pragma unroll
        for (int i = 0; i < 4; ++i) {
            const ushort16_t h0 = bf16rne(f[2*i]);
            const ushort16_t h1 = bf16rne(f[2*i+1]);
            const ushort16_t l0 = bf16rne(f[2*i]   - bf16tof(h0));
            const ushort16_t l1 = bf16rne(f[2*i+1] - bf16tof(h1));
            hw[i] = (uint32)h0 | ((uint32)h1 << 16);
            lw[i] = (uint32)l0 | ((uint32)l1 << 16);
        }
        cbfrag[(size_t)((c*4+s)*2 + 0)*64 + L] = make_uint4(hw[0],hw[1],hw[2],hw[3]);
        cbfrag[(size_t)((c*4+s)*2 + 1)*64 + L] = make_uint4(lw[0],lw[1],lw[2],lw[3]);
    } else {
        for (int k = tid; k < NK; k += 256) {
            const float* e = cb + (size_t)k * ND;
            float r[8];
#pragma unroll
            for (int j = 0; j < 8; ++j) {
                float s = __fmul_rn(e[j], e[j]);
#pragma unroll
                for (int i = 1; i < 8; ++i)
                    s = __fadd_rn(s, __fmul_rn(e[8*i+j], e[8*i+j]));
                r[j] = s;
            }
            enorm[k] = __fadd_rn(__fadd_rn(__fadd_rn(r[0],r[1]), __fadd_rn(r[2],r[3])),
                                 __fadd_rn(__fadd_rn(r[4],r[5]), __fadd_rn(r[6],r[7])));
        }
    }
}

// ---------------------------------------------------------------------------
// R6 main: MFMA bf16 hi/lo screen (error <= ~9e-5, margin 4e-4) + exact
// recheck of candidates with the R1-R5-verified bit-exact chain.
// Block = 256 thr = 4 waves; wave w owns z-rows [w*32, w*32+32); C layout
// puts one z-row per lane (col=lane&31) so argmin + candidate lists are
// per-lane. No barriers in the 16-chunk loop. Final combine: shfl_xor(32).
// ---------------------------------------------------------------------------
__global__ __launch_bounds__(256, 3) void vq_main(const float* __restrict__ z,
                                                  const float* __restrict__ cb,
                                                  const uint4* __restrict__ cbfrag,
                                                  const float* __restrict__ enorm,
                                                  float* __restrict__ qout,
                                                  float* __restrict__ idxout,
                                                  double* __restrict__ partials) {
    __shared__ __align__(16) char smem[46112];
    float*      zl   = (float*)smem;                    // 128 x STR fp32 (34816 B)
    float*      enl  = (float*)(smem + 34816);          // 512 fp32
    float*      znl  = (float*)(smem + 36864);          // 128 fp32
    ushort16_t* cand = (ushort16_t*)(smem + 37376);     // 128 x 2 x 16 (8192 B)
    int*        sfin = (int*)(smem + 45568);            // 128
    double*     sred = (double*)(smem + 46080);         // 4

    const int bi    = blockIdx.x;                       // 1024
    const int b     = bi >> 5;
    const int tbase = (bi & 31) * 128;
    const int tid   = threadIdx.x;
    const size_t zoff = (size_t)b * (ND * NT) + tbase;

    // ---- stage z (R5-verified transpose, perm rows, stride 68) ----
#pragma unroll
    for (int j = 0; j < 8; ++j) {
        const int qq = j * 256 + tid;
        const int i4 = qq & 31, d = qq >> 5;
        const float4 v = *(const float4*)(z + zoff + (size_t)d * NT + i4 * 4);
        const float vv[4] = {v.x, v.y, v.z, v.w};
#pragma unroll
        for (int c = 0; c < 4; ++c) {
            const int r = i4 * 4 + c;
            zl[PERM(r) * STR + d] = vv[c];
        }
    }
    for (int k = tid; k < NK; k += 256) enl[k] = enorm[k];
    __syncthreads();

    // ---- znorm (R5-verified numpy pairwise, tid<128) ----
    if (tid < 128) {
        const int r = tid;
        const float4* zr4 = (const float4*)&zl[PERM(r) * STR];
        float x[64];
#pragma unroll
        for (int wq = 0; wq < 16; ++wq) {
            const float4 t4 = zr4[wq];
            x[4*wq] = t4.x; x[4*wq+1] = t4.y; x[4*wq+2] = t4.z; x[4*wq+3] = t4.w;
        }
        float r8[8];
#pragma unroll
        for (int jj = 0; jj < 8; ++jj) {
            float s = __fmul_rn(x[jj], x[jj]);
#pragma unroll
            for (int ii = 1; ii < 8; ++ii)
                s = __fadd_rn(s, __fmul_rn(x[8*ii+jj], x[8*ii+jj]));
            r8[jj] = s;
        }
        znl[r] = __fadd_rn(__fadd_rn(__fadd_rn(r8[0],r8[1]), __fadd_rn(r8[2],r8[3])),
                           __fadd_rn(__fadd_rn(r8[4],r8[5]), __fadd_rn(r8[6],r8[7])));
    }

    // ---- build B-frags (z rows, bf16 hi/lo; same slot->d rule as prep) ----
    const int L    = tid & 63;
    const int w    = tid >> 6;
    const int h    = L >> 5;
    const int rowl = w * 32 + (L & 31);
    short8 bhf[4], blf[4];
    {
        const float* zrow = &zl[PERM(rowl) * STR];
#pragma unroll
        for (int s = 0; s < 4; ++s) {
            const int d0 = s * 16 + h * 8;
            const float4 pa = *(const float4*)(zrow + d0);
            const float4 pb = *(const float4*)(zrow + d0 + 4);
            const float f[8] = {pa.x, pa.y, pa.z, pa.w, pb.x, pb.y, pb.z, pb.w};
            uint32 hw[4], lw[4];
#pragma unroll
            for (int i = 0; i < 4; ++i) {
                const ushort16_t h0 = bf16rne(f[2*i]);
                const ushort16_t h1 = bf16rne(f[2*i+1]);
                const ushort16_t l0 = bf16rne(f[2*i]   - bf16tof(h0));
                const ushort16_t l1 = bf16rne(f[2*i+1] - bf16tof(h1));
                hw[i] = (uint32)h0 | ((uint32)h1 << 16);
                lw[i] = (uint32)l0 | ((uint32)l1 << 16);
            }
            union { uint4 u; short8 s8; } uh, ul;
            uh.u = make_uint4(hw[0],hw[1],hw[2],hw[3]);
            ul.u = make_uint4(lw[0],lw[1],lw[2],lw[3]);
            bhf[s] = uh.s8; blf[s] = ul.s8;
        }
    }
    __syncthreads();   // znl/zl stable before any wave races ahead

    // ---- screen: 16 chunks x 32 codes, 12 MFMA each, per-lane candidates ----
    float best  = __builtin_inff();
    int   bestk = 0;
    int   cnt   = 0;
    ushort16_t* mylist = cand + (rowl * 2 + h) * 16;

    for (int c = 0; c < 16; ++c) {
        union { uint4 u; short8 s8; } ah[4], al[4];
#pragma unroll
        for (int s = 0; s < 4; ++s) {
            ah[s].u = cbfrag[(size_t)((c*4+s)*2 + 0)*64 + L];
            al[s].u = cbfrag[(size_t)((c*4+s)*2 + 1)*64 + L];
        }
        f32x16 acc;
#pragma unroll
        for (int r = 0; r < 16; ++r) acc[r] = 0.0f;
#pragma unroll
        for (int s = 0; s < 4; ++s) {
            acc = __builtin_amdgcn_mfma_f32_32x32x16_bf16(ah[s].s8, bhf[s], acc, 0, 0, 0);
            acc = __builtin_amdgcn_mfma_f32_32x32x16_bf16(al[s].s8, bhf[s], acc, 0, 0, 0);
            acc = __builtin_amdgcn_mfma_f32_32x32x16_bf16(ah[s].s8, blf[s], acc, 0, 0, 0);
        }
#pragma unroll
        for (int r = 0; r < 16; ++r) {
            const int kc = c * 32 + ((r & 3) + 8 * (r >> 2) + 4 * h);  // C row = code
            const float en = enl[kc];
            const float sv = __builtin_fmaf(-2.0f, acc[r], en);
            if (sv < best) { best = sv; bestk = kc; }
            if (sv <= best + MARGIN && cnt < 16) { mylist[cnt] = (ushort16_t)kc; ++cnt; }
        }
    }

    // ---- exact recheck (bit-exact chain; own-lane data only, no barrier) ----
    float x[64];
    {
        const float4* zr4 = (const float4*)&zl[PERM(rowl) * STR];
#pragma unroll
        for (int i = 0; i < 16; ++i) {
            const float4 t4 = zr4[i];
            x[4*i] = t4.x; x[4*i+1] = t4.y; x[4*i+2] = t4.z; x[4*i+3] = t4.w;
        }
    }
    const float zn = znl[rowl];
    float bd; int bk = bestk;
    {
        const float* e = cb + (size_t)bestk * ND;
        float a = 0.0f;
#pragma unroll
        for (int d = 0; d < 64; ++d) a = __builtin_fmaf(x[d], e[d], a);
        bd = __fsub_rn(__fadd_rn(zn, enl[bestk]), __fmul_rn(2.0f, a));
    }
    for (int i = 0; i < cnt; ++i) {
        const int k2 = mylist[i];
        const float* e = cb + (size_t)k2 * ND;
        float a = 0.0f;
#pragma unroll
        for (int d = 0; d < 64; ++d) a = __builtin_fmaf(x[d], e[d], a);
        const float dv = __fsub_rn(__fadd_rn(zn, enl[k2]), __fmul_rn(2.0f, a));
        if (dv < bd || (dv == bd && k2 < bk)) { bd = dv; bk = k2; }
    }
    {   // combine the two code-halves of this row (lexicographic -> first occ.)
        const float obd = __shfl_xor(bd, 32);
        const int   obk = __shfl_xor(bk, 32);
        if (obd < bd || (obd == bd && obk < bk)) { bd = obd; bk = obk; }
    }
    if (h == 0) {
        sfin[rowl] = bk;
        idxout[(size_t)b * NT + tbase + rowl] = (float)bk;
    }
    __syncthreads();

    // ---- epilogue (R5 verbatim): straight-through out + loss ----
    double lsum = 0.0;
#pragma unroll 4
    for (int j = 0; j < 32; ++j) {
        const int qq = j * 256 + tid;
        const int ir = qq & 127, d = qq >> 7;
        const float zv = zl[PERM(ir) * STR + d];
        const float ev = cb[(size_t)sfin[ir] * ND + d];
        const float diff = __fsub_rn(ev, zv);              // quantized - zt
        qout[(size_t)b * (ND*NT) + (size_t)d * NT + tbase + ir] = __fadd_rn(zv, diff);
        lsum += (double)diff * (double)diff;
    }
#pragma unroll
    for (int off = 32; off > 0; off >>= 1) lsum += __shfl_down(lsum, off, 64);
    if ((tid & 63) == 0) sred[tid >> 6] = lsum;
    __syncthreads();
    if (tid == 0) partials[bi] = (sred[0] + sred[1]) + (sred[2] + sred[3]);
}

__global__ void finalize_kernel(const double* __restrict__ partials,
                                float* __restrict__ out0) {
    __shared__ double sred[4];
    const int tid = threadIdx.x;
    double s = partials[tid] + partials[tid + 256] + partials[tid + 512] + partials[tid + 768];
#pragma unroll
    for (int off = 32; off > 0; off >>= 1) s += __shfl_down(s, off, 64);
    if ((tid & 63) == 0) sred[tid >> 6] = s;
    __syncthreads();
    if (tid == 0) {
        const double m = ((sred[0] + sred[1]) + (sred[2] + sred[3]))
                         / (double)((size_t)NB * NT * ND);
        out0[0] = (float)(1.25 * m);       // codebook + 0.25*commitment
    }
}

extern "C" void kernel_launch(void* const* d_in, const int* in_sizes, int n_in,
                              void* d_out, int out_size, void* d_ws, size_t ws_size,
                              hipStream_t stream) {
    const float* z  = (const float*)d_in[0];
    const float* cb = (const float*)d_in[1];

    float* out      = (float*)d_out;
    float* loss_out = out;                                  // 1 elem
    float* qout     = out + 1;                              // B*D*T
    float* idxout   = out + 1 + (size_t)NB * ND * NT;       // B*T

    uint4*  cbfrag   = (uint4*)d_ws;                        // 131072 B
    float*  enorm    = (float*)((char*)d_ws + 131072);      // 2048 B
    double* partials = (double*)((char*)d_ws + 133120);     // 8192 B

    prep_kernel<<<17, 256, 0, stream>>>(cb, cbfrag, enorm);
    vq_main<<<1024, 256, 0, stream>>>(z, cb, cbfrag, enorm, qout, idxout, partials);
    finalize_kernel<<<1, 256, 0, stream>>>(partials, loss_out);
}

// Round 8
// 217.888 us; speedup vs baseline: 1.0008x; 1.0008x over previous
//
#include <hip/hip_runtime.h>

#define NB 32
#define ND 64
#define NT 4096
#define NK 512
#define NGRID 1024

typedef __attribute__((ext_vector_type(8))) short short8;
typedef __attribute__((ext_vector_type(16))) float f32x16;
typedef unsigned int uint32;
typedef unsigned short ushort16_t;

#define PERM(r) ((((r) & 7) * 16) + ((r) >> 3))
#define STR 68
#define ESTR 66
#define MARGIN 4e-4f
#define CAP 8   // 128 rows x 2 halves x 8 x 4B = 8192 B (R7 crash: CAP=16 -> 16 KB in an 8 KB slot)

__device__ __forceinline__ ushort16_t bf16rne(float f) {
    uint32 u = __float_as_uint(f);
    return (ushort16_t)((u + 0x7FFFu + ((u >> 16) & 1u)) >> 16);
}
__device__ __forceinline__ float bf16tof(ushort16_t h) {
    return __uint_as_float(((uint32)h) << 16);
}
// order-preserving float->uint with 9 low bits stolen for k (decode <= actual)
__device__ __forceinline__ uint32 encsv(float sv, int k) {
    uint32 u = __float_as_uint(sv);
    u = (u & 0x80000000u) ? ~u : (u | 0x80000000u);
    return (u & 0xFFFFFE00u) | (uint32)k;
}
__device__ __forceinline__ float decsv(uint32 v) {
    uint32 u = v & 0xFFFFFE00u;
    u = (u & 0x80000000u) ? (u & 0x7FFFFFFFu) : ~u;
    return __uint_as_float(u);
}

// ---------------------------------------------------------------------------
// prep: blocks 0..15 pack cb into MFMA A-frags (bf16 hi/lo; slot j of lane L,
// chunk c, kstep s = cb[c*32+(L&31)][s*16+(L>>5)*8+j]) — verified R6.
// Block 16: exact numpy-pairwise enorm[512] + zero loss accumulator/counter.
// ---------------------------------------------------------------------------
__global__ void prep_kernel(const float* __restrict__ cb,
                            uint4* __restrict__ cbfrag,
                            float* __restrict__ enorm,
                            double* __restrict__ loss_acc,
                            uint32* __restrict__ counter) {
    const int bi = blockIdx.x, tid = threadIdx.x;
    if (bi < 16) {
        const int t = bi * 256 + tid;
        const int c = t >> 8, rem = t & 255, s = rem >> 6, L = rem & 63;
        const int kcode = c * 32 + (L & 31);
        const int dbase = s * 16 + ((L >> 5) << 3);
        const float* src = cb + (size_t)kcode * 64 + dbase;
        const float4 pa = *(const float4*)src;
        const float4 pb = *(const float4*)(src + 4);
        const float f[8] = {pa.x, pa.y, pa.z, pa.w, pb.x, pb.y, pb.z, pb.w};
        uint32 hw[4], lw[4];
#pragma unroll
        for (int i = 0; i < 4; ++i) {
            const ushort16_t h0 = bf16rne(f[2*i]);
            const ushort16_t h1 = bf16rne(f[2*i+1]);
            const ushort16_t l0 = bf16rne(f[2*i]   - bf16tof(h0));
            const ushort16_t l1 = bf16rne(f[2*i+1] - bf16tof(h1));
            hw[i] = (uint32)h0 | ((uint32)h1 << 16);
            lw[i] = (uint32)l0 | ((uint32)l1 << 16);
        }
        cbfrag[(size_t)((c*4+s)*2 + 0)*64 + L] = make_uint4(hw[0],hw[1],hw[2],hw[3]);
        cbfrag[(size_t)((c*4+s)*2 + 1)*64 + L] = make_uint4(lw[0],lw[1],lw[2],lw[3]);
    } else {
        if (tid == 0) { *loss_acc = 0.0; *counter = 0u; }
        for (int k = tid; k < NK; k += 256) {
            const float* e = cb + (size_t)k * ND;
            float r[8];
#pragma unroll
            for (int j = 0; j < 8; ++j) {
                float s = __fmul_rn(e[j], e[j]);
#pragma unroll
                for (int i = 1; i < 8; ++i)
                    s = __fadd_rn(s, __fmul_rn(e[8*i+j], e[8*i+j]));
                r[j] = s;
            }
            enorm[k] = __fadd_rn(__fadd_rn(__fadd_rn(r[0],r[1]), __fadd_rn(r[2],r[3])),
                                 __fadd_rn(__fadd_rn(r[4],r[5]), __fadd_rn(r[6],r[7])));
        }
    }
}

// exact dist for (row in zl, code k2) — the R1-R6 verified bit-exact chain
__device__ __forceinline__ float exact_dist(const float* __restrict__ zrow,
                                            const float* __restrict__ cb,
                                            const float* __restrict__ enl,
                                            float zn, int k2) {
    const float4* e4 = (const float4*)(cb + (size_t)k2 * ND);
    float a = 0.0f;
#pragma unroll
    for (int w = 0; w < 16; ++w) {
        const float4 ev = e4[w];
        const float4 zv = *(const float4*)(zrow + 4 * w);
        a = __builtin_fmaf(zv.x, ev.x, a);
        a = __builtin_fmaf(zv.y, ev.y, a);
        a = __builtin_fmaf(zv.z, ev.z, a);
        a = __builtin_fmaf(zv.w, ev.w, a);
    }
    return __fsub_rn(__fadd_rn(zn, enl[k2]), __fmul_rn(2.0f, a));
}

// ---------------------------------------------------------------------------
// R8 main: MFMA screen (R6-verified) + final-best-filtered exact recheck
// (inline from LDS list — no runtime-indexed private array) + LDS-staged
// epilogue + fused last-block loss finalize.
// ---------------------------------------------------------------------------
__global__ __launch_bounds__(256, 3) void vq_main(const float* __restrict__ z,
                                                  const float* __restrict__ cb,
                                                  const uint4* __restrict__ cbfrag,
                                                  const float* __restrict__ enorm,
                                                  float* __restrict__ qout,
                                                  float* __restrict__ idxout,
                                                  double* __restrict__ loss_acc,
                                                  uint32* __restrict__ counter,
                                                  float* __restrict__ out0) {
    __shared__ __align__(16) char smem[46112];
    float*  zl   = (float*)smem;                 // 128 x STR fp32 (34816 B); later ech 128 x ESTR
    float*  enl  = (float*)(smem + 34816);       // 512 fp32
    float*  znl  = (float*)(smem + 36864);       // 128 fp32
    uint32* cand = (uint32*)(smem + 37376);      // 128 x 2 x CAP uint32 (8192 B)
    int*    sfin = (int*)(smem + 45568);         // 128
    double* sred = (double*)(smem + 46080);      // 4

    const int bi    = blockIdx.x;                // 1024
    const int b     = bi >> 5;
    const int tbase = (bi & 31) * 128;
    const int tid   = threadIdx.x;
    const size_t zoff = (size_t)b * (ND * NT) + tbase;

    // ---- stage z (R5/R6-verified transpose, perm rows, stride 68) ----
#pragma unroll
    for (int j = 0; j < 8; ++j) {
        const int qq = j * 256 + tid;
        const int i4 = qq & 31, d = qq >> 5;
        const float4 v = *(const float4*)(z + zoff + (size_t)d * NT + i4 * 4);
        const float vv[4] = {v.x, v.y, v.z, v.w};
#pragma unroll
        for (int c = 0; c < 4; ++c) {
            const int r = i4 * 4 + c;
            zl[PERM(r) * STR + d] = vv[c];
        }
    }
    for (int k = tid; k < NK; k += 256) enl[k] = enorm[k];
    __syncthreads();

    // ---- znorm (verified numpy pairwise, tid<128) ----
    if (tid < 128) {
        const int r = tid;
        const float4* zr4 = (const float4*)&zl[PERM(r) * STR];
        float x[64];
#pragma unroll
        for (int wq = 0; wq < 16; ++wq) {
            const float4 t4 = zr4[wq];
            x[4*wq] = t4.x; x[4*wq+1] = t4.y; x[4*wq+2] = t4.z; x[4*wq+3] = t4.w;
        }
        float r8[8];
#pragma unroll
        for (int jj = 0; jj < 8; ++jj) {
            float s = __fmul_rn(x[jj], x[jj]);
#pragma unroll
            for (int ii = 1; ii < 8; ++ii)
                s = __fadd_rn(s, __fmul_rn(x[8*ii+jj], x[8*ii+jj]));
            r8[jj] = s;
        }
        znl[r] = __fadd_rn(__fadd_rn(__fadd_rn(r8[0],r8[1]), __fadd_rn(r8[2],r8[3])),
                           __fadd_rn(__fadd_rn(r8[4],r8[5]), __fadd_rn(r8[6],r8[7])));
    }

    // ---- build B-frags (z rows, bf16 hi/lo; same slot->d rule as prep) ----
    const int L    = tid & 63;
    const int w    = tid >> 6;
    const int h    = L >> 5;
    const int rowl = w * 32 + (L & 31);
    short8 bhf[4], blf[4];
    {
        const float* zrow = &zl[PERM(rowl) * STR];
#pragma unroll
        for (int s = 0; s < 4; ++s) {
            const int d0 = s * 16 + h * 8;
            const float4 pa = *(const float4*)(zrow + d0);
            const float4 pb = *(const float4*)(zrow + d0 + 4);
            const float f[8] = {pa.x, pa.y, pa.z, pa.w, pb.x, pb.y, pb.z, pb.w};
            uint32 hw[4], lw[4];
#pragma unroll
            for (int i = 0; i < 4; ++i) {
                const ushort16_t h0 = bf16rne(f[2*i]);
                const ushort16_t h1 = bf16rne(f[2*i+1]);
                const ushort16_t l0 = bf16rne(f[2*i]   - bf16tof(h0));
                const ushort16_t l1 = bf16rne(f[2*i+1] - bf16tof(h1));
                hw[i] = (uint32)h0 | ((uint32)h1 << 16);
                lw[i] = (uint32)l0 | ((uint32)l1 << 16);
            }
            union { uint4 u; short8 s8; } uh, ul;
            uh.u = make_uint4(hw[0],hw[1],hw[2],hw[3]);
            ul.u = make_uint4(lw[0],lw[1],lw[2],lw[3]);
            bhf[s] = uh.s8; blf[s] = ul.s8;
        }
    }
    __syncthreads();

    // ---- screen (R6-verified): 16 chunks x 32 codes, per-lane candidates ----
    float best  = __builtin_inff();
    int   bestk = 0;
    int   cnt   = 0;
    int   ovf   = 0;
    uint32* mylist = cand + (rowl * 2 + h) * CAP;   // max idx 2047 < 2048 ok

    for (int c = 0; c < 16; ++c) {
        union { uint4 u; short8 s8; } ah[4], al[4];
#pragma unroll
        for (int s = 0; s < 4; ++s) {
            ah[s].u = cbfrag[(size_t)((c*4+s)*2 + 0)*64 + L];
            al[s].u = cbfrag[(size_t)((c*4+s)*2 + 1)*64 + L];
        }
        f32x16 acc;
#pragma unroll
        for (int r = 0; r < 16; ++r) acc[r] = 0.0f;
#pragma unroll
        for (int s = 0; s < 4; ++s) {
            acc = __builtin_amdgcn_mfma_f32_32x32x16_bf16(ah[s].s8, bhf[s], acc, 0, 0, 0);
            acc = __builtin_amdgcn_mfma_f32_32x32x16_bf16(al[s].s8, bhf[s], acc, 0, 0, 0);
            acc = __builtin_amdgcn_mfma_f32_32x32x16_bf16(ah[s].s8, blf[s], acc, 0, 0, 0);
        }
#pragma unroll
        for (int r = 0; r < 16; ++r) {
            const int kc = c * 32 + ((r & 3) + 8 * (r >> 2) + 4 * h);
            const float sv = __builtin_fmaf(-2.0f, acc[r], enl[kc]);
            if (sv < best) { best = sv; bestk = kc; }
            if (sv <= best + MARGIN) {
                if (cnt == CAP) {            // compact out stale entries (rare)
                    int nc = 0;
                    for (int i = 0; i < CAP; ++i) {
                        const uint32 e = mylist[i];
                        if (decsv(e) <= best + MARGIN) mylist[nc++] = e;
                    }
                    cnt = nc;
                }
                if (cnt < CAP) mylist[cnt++] = encsv(sv, kc);
                else ovf = 1;
            }
        }
    }

    // ---- filtered exact recheck, inline from LDS list ----
    const float* zrow = &zl[PERM(rowl) * STR];
    const float  zn   = znl[rowl];
    const float  ob   = __shfl_xor(best, 32);
    const float  mb   = fminf(best, ob);     // final screen best of the row
    const int    oovf = __shfl_xor(ovf, 32);

    float bd = __builtin_inff();
    int   bk = 0x7FFFFFFF;
    if (ovf | oovf) {
        // rare fallback: exact scan of this lane's full code subset, asc k
        for (int c = 0; c < 16; ++c)
#pragma unroll
            for (int qd = 0; qd < 4; ++qd)
#pragma unroll
                for (int i = 0; i < 4; ++i) {
                    const int k2 = c * 32 + qd * 8 + h * 4 + i;
                    const float dv = exact_dist(zrow, cb, enl, zn, k2);
                    if (dv < bd || (dv == bd && k2 < bk)) { bd = dv; bk = k2; }
                }
    } else {
        for (int i = 0; i < cnt; ++i) {      // entries ascend in k
            const uint32 e = mylist[i];
            if (decsv(e) > mb + MARGIN) continue;   // stale vs final best
            const int k2 = (int)(e & 511u);
            const float dv = exact_dist(zrow, cb, enl, zn, k2);
            if (dv < bd || (dv == bd && k2 < bk)) { bd = dv; bk = k2; }
        }
    }
    {   // cross-half lexicographic combine (first occurrence)
        const float obd = __shfl_xor(bd, 32);
        const int   obk = __shfl_xor(bk, 32);
        if (obd < bd || (obd == bd && obk < bk)) { bd = obd; bk = obk; }
    }
    if (h == 0) {
        sfin[rowl] = bk;
        idxout[(size_t)b * NT + tbase + rowl] = (float)bk;
    }
    __syncthreads();       // all recheck reads of zl done; sfin visible

    // ---- stage chosen rows into ech (reuses zl space) ----
    float* ech = zl;       // 128 x ESTR floats = 33792 B <= 34816
#pragma unroll
    for (int j = 0; j < 8; ++j) {
        const int qq  = j * 256 + tid;
        const int row = qq >> 4, d4 = qq & 15;
        const float4 v = *(const float4*)(cb + (size_t)sfin[row] * ND + d4 * 4);
        float* dst = &ech[row * ESTR + d4 * 4];
        *(float2*)(dst)     = make_float2(v.x, v.y);
        *(float2*)(dst + 2) = make_float2(v.z, v.w);
    }
    __syncthreads();

    // ---- epilogue: z re-read from global (coalesced), e from LDS ----
    double lsum = 0.0;
#pragma unroll 4
    for (int j = 0; j < 32; ++j) {
        const int qq = j * 256 + tid;
        const int ir = qq & 127, d = qq >> 7;
        const float zv = z[zoff + (size_t)d * NT + ir];
        const float ev = ech[ir * ESTR + d];
        const float diff = __fsub_rn(ev, zv);               // quantized - zt
        qout[(size_t)b * (ND*NT) + (size_t)d * NT + tbase + ir] = __fadd_rn(zv, diff);
        lsum += (double)diff * (double)diff;
    }
#pragma unroll
    for (int off = 32; off > 0; off >>= 1) lsum += __shfl_down(lsum, off, 64);
    if ((tid & 63) == 0) sred[tid >> 6] = lsum;
    __syncthreads();

    // ---- fused finalize: last block computes the loss output ----
    if (tid == 0) {
        const double bsum = (sred[0] + sred[1]) + (sred[2] + sred[3]);
        atomicAdd(loss_acc, bsum);
        __threadfence();
        const uint32 old = atomicAdd(counter, 1u);
        if (old == (uint32)(NGRID - 1)) {
            __threadfence();
            const double tot = *(volatile double*)loss_acc;
            const double m = tot / (double)((size_t)NB * NT * ND);
            out0[0] = (float)(1.25 * m);   // codebook + 0.25*commitment
        }
    }
}

extern "C" void kernel_launch(void* const* d_in, const int* in_sizes, int n_in,
                              void* d_out, int out_size, void* d_ws, size_t ws_size,
                              hipStream_t stream) {
    const float* z  = (const float*)d_in[0];
    const float* cb = (const float*)d_in[1];

    float* out      = (float*)d_out;
    float* loss_out = out;                                  // 1 elem
    float* qout     = out + 1;                              // B*D*T
    float* idxout   = out + 1 + (size_t)NB * ND * NT;       // B*T

    uint4*  cbfrag   = (uint4*)d_ws;                        // 131072 B
    float*  enorm    = (float*)((char*)d_ws + 131072);      // 2048 B
    double* loss_acc = (double*)((char*)d_ws + 133120);     // 8 B
    uint32* counter  = (uint32*)((char*)d_ws + 133128);     // 4 B

    prep_kernel<<<17, 256, 0, stream>>>(cb, cbfrag, enorm, loss_acc, counter);
    vq_main<<<NGRID, 256, 0, stream>>>(z, cb, cbfrag, enorm, qout, idxout,
                                       loss_acc, counter, loss_out);
}

// Round 9
// 200.877 us; speedup vs baseline: 1.0855x; 1.0847x over previous
//
#include <hip/hip_runtime.h>

#define NB 32
#define ND 64
#define NT 4096
#define NK 512
#define NGRID 1024

typedef __attribute__((ext_vector_type(8))) short short8;
typedef __attribute__((ext_vector_type(16))) float f32x16;
typedef unsigned int uint32;
typedef unsigned short ushort16_t;

#define PERM(r) ((((r) & 7) * 16) + ((r) >> 3))
#define STR 68
#define ESTR 66
#define MARGIN 4e-4f
#define RCAP 4

__device__ __forceinline__ ushort16_t bf16rne(float f) {
    uint32 u = __float_as_uint(f);
    return (ushort16_t)((u + 0x7FFFu + ((u >> 16) & 1u)) >> 16);
}
__device__ __forceinline__ float bf16tof(ushort16_t h) {
    return __uint_as_float(((uint32)h) << 16);
}

// ---------------------------------------------------------------------------
// prep (verified R6-R8): blocks 0..15 pack cb into MFMA A-frags (bf16 hi/lo);
// block 16: exact numpy-pairwise enorm + zero loss accumulator/counter.
// ---------------------------------------------------------------------------
__global__ void prep_kernel(const float* __restrict__ cb,
                            uint4* __restrict__ cbfrag,
                            float* __restrict__ enorm,
                            double* __restrict__ loss_acc,
                            uint32* __restrict__ counter) {
    const int bi = blockIdx.x, tid = threadIdx.x;
    if (bi < 16) {
        const int t = bi * 256 + tid;
        const int c = t >> 8, rem = t & 255, s = rem >> 6, L = rem & 63;
        const int kcode = c * 32 + (L & 31);
        const int dbase = s * 16 + ((L >> 5) << 3);
        const float* src = cb + (size_t)kcode * 64 + dbase;
        const float4 pa = *(const float4*)src;
        const float4 pb = *(const float4*)(src + 4);
        const float f[8] = {pa.x, pa.y, pa.z, pa.w, pb.x, pb.y, pb.z, pb.w};
        uint32 hw[4], lw[4];
#pragma unroll
        for (int i = 0; i < 4; ++i) {
            const ushort16_t h0 = bf16rne(f[2*i]);
            const ushort16_t h1 = bf16rne(f[2*i+1]);
            const ushort16_t l0 = bf16rne(f[2*i]   - bf16tof(h0));
            const ushort16_t l1 = bf16rne(f[2*i+1] - bf16tof(h1));
            hw[i] = (uint32)h0 | ((uint32)h1 << 16);
            lw[i] = (uint32)l0 | ((uint32)l1 << 16);
        }
        cbfrag[(size_t)((c*4+s)*2 + 0)*64 + L] = make_uint4(hw[0],hw[1],hw[2],hw[3]);
        cbfrag[(size_t)((c*4+s)*2 + 1)*64 + L] = make_uint4(lw[0],lw[1],lw[2],lw[3]);
    } else {
        if (tid == 0) { *loss_acc = 0.0; *counter = 0u; }
        for (int k = tid; k < NK; k += 256) {
            const float* e = cb + (size_t)k * ND;
            float r[8];
#pragma unroll
            for (int j = 0; j < 8; ++j) {
                float s = __fmul_rn(e[j], e[j]);
#pragma unroll
                for (int i = 1; i < 8; ++i)
                    s = __fadd_rn(s, __fmul_rn(e[8*i+j], e[8*i+j]));
                r[j] = s;
            }
            enorm[k] = __fadd_rn(__fadd_rn(__fadd_rn(r[0],r[1]), __fadd_rn(r[2],r[3])),
                                 __fadd_rn(__fadd_rn(r[4],r[5]), __fadd_rn(r[6],r[7])));
        }
    }
}

// exact dist — the R1-R8 verified bit-exact chain
__device__ __forceinline__ float exact_dist(const float* __restrict__ zrow,
                                            const float* __restrict__ cb,
                                            const float* __restrict__ enl,
                                            float zn, int k2) {
    const float4* e4 = (const float4*)(cb + (size_t)k2 * ND);
    float a = 0.0f;
#pragma unroll
    for (int w = 0; w < 16; ++w) {
        const float4 ev = e4[w];
        const float4 zv = *(const float4*)(zrow + 4 * w);
        a = __builtin_fmaf(zv.x, ev.x, a);
        a = __builtin_fmaf(zv.y, ev.y, a);
        a = __builtin_fmaf(zv.z, ev.z, a);
        a = __builtin_fmaf(zv.w, ev.w, a);
    }
    return __fsub_rn(__fadd_rn(zn, enl[k2]), __fmul_rn(2.0f, a));
}

// ---------------------------------------------------------------------------
// R9 main: two-pass MFMA screen. Pass A: branchless best-tracking only,
// cbfrag double-buffer-prefetched. Pass B: re-MFMA, collect k with
// sv <= final_best + MARGIN (rare, ~0.07/row, no staleness/compaction).
// Rows with no rival skip exact work (M > 2*eps proves screen-best = ref
// argmin). Rivals resolved with the verified exact chain, lexicographic.
// ---------------------------------------------------------------------------
__global__ __launch_bounds__(256, 3) void vq_main(const float* __restrict__ z,
                                                  const float* __restrict__ cb,
                                                  const uint4* __restrict__ cbfrag,
                                                  const float* __restrict__ enorm,
                                                  float* __restrict__ qout,
                                                  float* __restrict__ idxout,
                                                  double* __restrict__ loss_acc,
                                                  uint32* __restrict__ counter,
                                                  float* __restrict__ out0) {
    __shared__ __align__(16) char smem[46112];
    float*       zl   = (float*)smem;              // 128 x STR (34816 B); later ech
    float*       enl  = (float*)(smem + 34816);    // 512
    float*       znl  = (float*)(smem + 36864);    // 128
    ushort16_t*  cand = (ushort16_t*)(smem + 37376); // 128 x 2 x RCAP u16 (2048 B used)
    int*         sfin = (int*)(smem + 45568);      // 128
    double*      sred = (double*)(smem + 46080);   // 4

    const int bi    = blockIdx.x;                  // 1024
    const int b     = bi >> 5;
    const int tbase = (bi & 31) * 128;
    const int tid   = threadIdx.x;
    const size_t zoff = (size_t)b * (ND * NT) + tbase;

    // ---- stage z (verified transpose) ----
#pragma unroll
    for (int j = 0; j < 8; ++j) {
        const int qq = j * 256 + tid;
        const int i4 = qq & 31, d = qq >> 5;
        const float4 v = *(const float4*)(z + zoff + (size_t)d * NT + i4 * 4);
        const float vv[4] = {v.x, v.y, v.z, v.w};
#pragma unroll
        for (int c = 0; c < 4; ++c) {
            const int r = i4 * 4 + c;
            zl[PERM(r) * STR + d] = vv[c];
        }
    }
    for (int k = tid; k < NK; k += 256) enl[k] = enorm[k];
    __syncthreads();

    // ---- znorm (verified numpy pairwise, tid<128) ----
    if (tid < 128) {
        const int r = tid;
        const float4* zr4 = (const float4*)&zl[PERM(r) * STR];
        float x[64];
#pragma unroll
        for (int wq = 0; wq < 16; ++wq) {
            const float4 t4 = zr4[wq];
            x[4*wq] = t4.x; x[4*wq+1] = t4.y; x[4*wq+2] = t4.z; x[4*wq+3] = t4.w;
        }
        float r8[8];
#pragma unroll
        for (int jj = 0; jj < 8; ++jj) {
            float s = __fmul_rn(x[jj], x[jj]);
#pragma unroll
            for (int ii = 1; ii < 8; ++ii)
                s = __fadd_rn(s, __fmul_rn(x[8*ii+jj], x[8*ii+jj]));
            r8[jj] = s;
        }
        znl[r] = __fadd_rn(__fadd_rn(__fadd_rn(r8[0],r8[1]), __fadd_rn(r8[2],r8[3])),
                           __fadd_rn(__fadd_rn(r8[4],r8[5]), __fadd_rn(r8[6],r8[7])));
    }

    // ---- B-frags (verified: z rows bf16 hi/lo, same slot->d rule as prep) ----
    const int L    = tid & 63;
    const int w    = tid >> 6;
    const int h    = L >> 5;
    const int rowl = w * 32 + (L & 31);
    short8 bhf[4], blf[4];
    {
        const float* zrow = &zl[PERM(rowl) * STR];
#pragma unroll
        for (int s = 0; s < 4; ++s) {
            const int d0 = s * 16 + h * 8;
            const float4 pa = *(const float4*)(zrow + d0);
            const float4 pb = *(const float4*)(zrow + d0 + 4);
            const float f[8] = {pa.x, pa.y, pa.z, pa.w, pb.x, pb.y, pb.z, pb.w};
            uint32 hw[4], lw[4];
#pragma unroll
            for (int i = 0; i < 4; ++i) {
                const ushort16_t h0 = bf16rne(f[2*i]);
                const ushort16_t h1 = bf16rne(f[2*i+1]);
                const ushort16_t l0 = bf16rne(f[2*i]   - bf16tof(h0));
                const ushort16_t l1 = bf16rne(f[2*i+1] - bf16tof(h1));
                hw[i] = (uint32)h0 | ((uint32)h1 << 16);
                lw[i] = (uint32)l0 | ((uint32)l1 << 16);
            }
            union { uint4 u; short8 s8; } uh, ul;
            uh.u = make_uint4(hw[0],hw[1],hw[2],hw[3]);
            ul.u = make_uint4(lw[0],lw[1],lw[2],lw[3]);
            bhf[s] = uh.s8; blf[s] = ul.s8;
        }
    }
    __syncthreads();

    // ---- PASS A: branchless screen, prefetched cbfrag ----
    float best  = __builtin_inff();
    int   bestk = 0;
    {
        uint4 buf0[8], buf1[8];
#pragma unroll
        for (int p = 0; p < 8; ++p) buf0[p] = cbfrag[(size_t)p * 64 + L];
#pragma unroll 2
        for (int c = 0; c < 16; ++c) {
            const uint4* cur = (c & 1) ? buf1 : buf0;
            uint4*       nxt = (c & 1) ? buf0 : buf1;
#pragma unroll
            for (int p = 0; p < 8; ++p)            // c=15 prefetch hits ws slack
                nxt[p] = cbfrag[(size_t)((c + 1) * 8 + p) * 64 + L];
            f32x16 acc;
#pragma unroll
            for (int r = 0; r < 16; ++r) acc[r] = 0.0f;
#pragma unroll
            for (int s = 0; s < 4; ++s) {
                union { uint4 u; short8 s8; } ah, al;
                ah.u = cur[s * 2 + 0];
                al.u = cur[s * 2 + 1];
                acc = __builtin_amdgcn_mfma_f32_32x32x16_bf16(ah.s8, bhf[s], acc, 0, 0, 0);
                acc = __builtin_amdgcn_mfma_f32_32x32x16_bf16(al.s8, bhf[s], acc, 0, 0, 0);
                acc = __builtin_amdgcn_mfma_f32_32x32x16_bf16(ah.s8, blf[s], acc, 0, 0, 0);
            }
#pragma unroll
            for (int r = 0; r < 16; ++r) {
                const int kc = c * 32 + ((r & 3) + 8 * (r >> 2) + 4 * h);
                const float sv = __builtin_fmaf(-2.0f, acc[r], enl[kc]);
                if (sv < best) { best = sv; bestk = kc; }   // 2 cndmasks, no branch
            }
        }
    }
    // cross-half combine of screen best (lexicographic -> first occurrence)
    {
        const float ob  = __shfl_xor(best, 32);
        const int   obk = __shfl_xor(bestk, 32);
        if (ob < best || (ob == best && obk < bestk)) { best = ob; bestk = obk; }
    }
    const float thresh = best + MARGIN;

    // ---- PASS B: collect rivals vs final threshold (rare appends) ----
    int myc = 0, ovf = 0;
    ushort16_t* mylist = cand + (rowl * 2 + h) * RCAP;
    {
        uint4 buf0[8], buf1[8];
#pragma unroll
        for (int p = 0; p < 8; ++p) buf0[p] = cbfrag[(size_t)p * 64 + L];
#pragma unroll 2
        for (int c = 0; c < 16; ++c) {
            const uint4* cur = (c & 1) ? buf1 : buf0;
            uint4*       nxt = (c & 1) ? buf0 : buf1;
#pragma unroll
            for (int p = 0; p < 8; ++p)
                nxt[p] = cbfrag[(size_t)((c + 1) * 8 + p) * 64 + L];
            f32x16 acc;
#pragma unroll
            for (int r = 0; r < 16; ++r) acc[r] = 0.0f;
#pragma unroll
            for (int s = 0; s < 4; ++s) {
                union { uint4 u; short8 s8; } ah, al;
                ah.u = cur[s * 2 + 0];
                al.u = cur[s * 2 + 1];
                acc = __builtin_amdgcn_mfma_f32_32x32x16_bf16(ah.s8, bhf[s], acc, 0, 0, 0);
                acc = __builtin_amdgcn_mfma_f32_32x32x16_bf16(al.s8, bhf[s], acc, 0, 0, 0);
                acc = __builtin_amdgcn_mfma_f32_32x32x16_bf16(ah.s8, blf[s], acc, 0, 0, 0);
            }
#pragma unroll
            for (int r = 0; r < 16; ++r) {
                const int kc = c * 32 + ((r & 3) + 8 * (r >> 2) + 4 * h);
                const float sv = __builtin_fmaf(-2.0f, acc[r], enl[kc]);
                if (sv <= thresh && kc != bestk) {
                    if (myc < RCAP) mylist[myc++] = (ushort16_t)kc;
                    else ovf = 1;
                }
            }
        }
    }

    // ---- exact resolution (only rows with rivals; verified chain) ----
    const float* zrow = &zl[PERM(rowl) * STR];
    const float  zn   = znl[rowl];
    const int    totr = myc + __shfl_xor(myc, 32);
    const int    aovf = ovf | __shfl_xor(ovf, 32);

    int bk;
    if (aovf) {
        // overflow fallback: full exact scan of this half's codes, asc k
        float bd = __builtin_inff(); bk = 0x7FFFFFFF;
        for (int c = 0; c < 16; ++c)
#pragma unroll
            for (int qd = 0; qd < 4; ++qd)
#pragma unroll
                for (int i = 0; i < 4; ++i) {
                    const int k2 = c * 32 + qd * 8 + h * 4 + i;
                    const float dv = exact_dist(zrow, cb, enl, zn, k2);
                    if (dv < bd || (dv == bd && k2 < bk)) { bd = dv; bk = k2; }
                }
        const float obd = __shfl_xor(bd, 32);
        const int   obk = __shfl_xor(bk, 32);
        if (obd < bd || (obd == bd && obk < bk)) bk = obk;
    } else if (totr > 0) {
        float bd = __builtin_inff(); bk = 0x7FFFFFFF;
        if (((bestk >> 2) & 1) == h) {       // owner half exact-dots screen best
            bd = exact_dist(zrow, cb, enl, zn, bestk);
            bk = bestk;
        }
        for (int i = 0; i < myc; ++i) {
            const int k2 = mylist[i];
            const float dv = exact_dist(zrow, cb, enl, zn, k2);
            if (dv < bd || (dv == bd && k2 < bk)) { bd = dv; bk = k2; }
        }
        const float obd = __shfl_xor(bd, 32);
        const int   obk = __shfl_xor(bk, 32);
        if (obd < bd || (obd == bd && obk < bk)) bk = obk;
    } else {
        bk = bestk;                           // no rival: screen best is proven
    }
    if (h == 0) {
        sfin[rowl] = bk;
        idxout[(size_t)b * NT + tbase + rowl] = (float)bk;
    }
    __syncthreads();

    // ---- staged epilogue (R8 verbatim) ----
    float* ech = zl;
#pragma unroll
    for (int j = 0; j < 8; ++j) {
        const int qq  = j * 256 + tid;
        const int row = qq >> 4, d4 = qq & 15;
        const float4 v = *(const float4*)(cb + (size_t)sfin[row] * ND + d4 * 4);
        float* dst = &ech[row * ESTR + d4 * 4];
        *(float2*)(dst)     = make_float2(v.x, v.y);
        *(float2*)(dst + 2) = make_float2(v.z, v.w);
    }
    __syncthreads();

    double lsum = 0.0;
#pragma unroll 4
    for (int j = 0; j < 32; ++j) {
        const int qq = j * 256 + tid;
        const int ir = qq & 127, d = qq >> 7;
        const float zv = z[zoff + (size_t)d * NT + ir];
        const float ev = ech[ir * ESTR + d];
        const float diff = __fsub_rn(ev, zv);              // quantized - zt
        qout[(size_t)b * (ND*NT) + (size_t)d * NT + tbase + ir] = __fadd_rn(zv, diff);
        lsum += (double)diff * (double)diff;
    }
#pragma unroll
    for (int off = 32; off > 0; off >>= 1) lsum += __shfl_down(lsum, off, 64);
    if ((tid & 63) == 0) sred[tid >> 6] = lsum;
    __syncthreads();

    if (tid == 0) {
        const double bsum = (sred[0] + sred[1]) + (sred[2] + sred[3]);
        atomicAdd(loss_acc, bsum);
        __threadfence();
        const uint32 old = atomicAdd(counter, 1u);
        if (old == (uint32)(NGRID - 1)) {
            __threadfence();
            const double tot = *(volatile double*)loss_acc;
            const double m = tot / (double)((size_t)NB * NT * ND);
            out0[0] = (float)(1.25 * m);   // codebook + 0.25*commitment
        }
    }
}

extern "C" void kernel_launch(void* const* d_in, const int* in_sizes, int n_in,
                              void* d_out, int out_size, void* d_ws, size_t ws_size,
                              hipStream_t stream) {
    const float* z  = (const float*)d_in[0];
    const float* cb = (const float*)d_in[1];

    float* out      = (float*)d_out;
    float* loss_out = out;                                  // 1 elem
    float* qout     = out + 1;                              // B*D*T
    float* idxout   = out + 1 + (size_t)NB * ND * NT;       // B*T

    // cbfrag 131072 B + 8192 B slack (c=15 prefetch overrun target, unused data)
    uint4*  cbfrag   = (uint4*)d_ws;
    float*  enorm    = (float*)((char*)d_ws + 139264);      // 2048 B
    double* loss_acc = (double*)((char*)d_ws + 141312);     // 8 B
    uint32* counter  = (uint32*)((char*)d_ws + 141320);     // 4 B

    prep_kernel<<<17, 256, 0, stream>>>(cb, cbfrag, enorm, loss_acc, counter);
    vq_main<<<NGRID, 256, 0, stream>>>(z, cb, cbfrag, enorm, qout, idxout,
                                       loss_acc, counter, loss_out);
}